// Round 14
// baseline (650.949 us; speedup 1.0000x reference)
//
#include <hip/hip_runtime.h>

// Modulated deformable conv2d, fp32 in/out, bf16 MFMA core.
// B=4, C=64, H=W=128, O=64, K=3x3, stride=1, pad=1, dil=1, og=1, groups=1.
//
// Round 19: corner-split MFMA. Bilinear weights commute out of the channel
// contraction: out[o,p] = sum_i w_i[p] * (sum_c W[o,c] X_i[p,c]). Feed RAW
// LDS corner data into the MFMA (B operand) and fold w_i into the f32
// accumulator after. Deletes the 144-VALU/tap blend that sat serially
// between ds_read and MFMA (the stall chain r16-r18 failed to hide).
// Enabler (m89/m120 layouts): A and B fragments have the SAME lane map on
// 16x16x32 (lane&15 = non-K, quad*8+j = K), so swapping operands (A=weight,
// B=pixel) reuses wfr and the g/h gathers unchanged. Per tap: 4 corners x
// 8 MFMA (C=0 first half) + 64 combine-FMA. New D map: row=o-sub, col=pixel
// -> epilogue = 16 scalar stores (32B segments). Rest = r18 verbatim.
// Fragment layouts: A[m=lane&15][k=quad*8+j], B[k=quad*8+j][n=lane&15],
// D[row=quad*4+reg][col=lane&15].

#define BB 4
#define CC 64
#define HH 128
#define WW 128
#define OO 64
#define KHW 3
#define KK 9
#define HW (HH * WW)

typedef __bf16 bf16_t;
typedef bf16_t bf16x8 __attribute__((ext_vector_type(8)));
typedef float f32x4 __attribute__((ext_vector_type(4)));

// ---- weight [O][C][3][3] fp32 -> fragment order bf16 ----
// wf element index: ((tap*2+q)*4+nt)*64*8 + lane*8 + j
//   holds W[o = nt*16 + (lane&15)][c = q*32 + (lane>>4)*8 + j][tap]
// (valid as A-fragment: m=lane&15 -> o-sub, k=quad*8+j -> c-sub)
__global__ void wfrag_kernel(const float* __restrict__ w,
                             bf16_t* __restrict__ wf) {
    int i = blockIdx.x * blockDim.x + threadIdx.x;
    if (i >= OO * CC * KK) return;
    int j    = i & 7;
    int lane = (i >> 3) & 63;
    int nt   = (i >> 9) & 3;
    int q    = (i >> 11) & 1;
    int k    = i >> 12;
    int o = nt * 16 + (lane & 15);
    int c = q * 32 + ((lane >> 4) << 3) + j;
    wf[i] = (bf16_t)w[(o * CC + c) * KK + k];
}

__global__ __launch_bounds__(256, 4) void deform_conv_mfma(
    const float* __restrict__ x, const float* __restrict__ offset,
    const float* __restrict__ mask, const bf16x8* __restrict__ wf,
    const float* __restrict__ bias, float* __restrict__ out) {
    const int t    = threadIdx.x;
    // XCD-aware bijective swizzle: grid = 1024 = 8 * 128.
    const int wg   = (blockIdx.x & 7) * ((BB * 256) >> 3) + (blockIdx.x >> 3);
    const int b    = wg >> 8;
    const int ti   = wg & 255;                 // tile id: 16x16 tiles of 8x8
    const int r0   = ((ti >> 4) << 3);         // tile top row
    const int c0   = ((ti & 15) << 3);         // tile left col
    const int lane = t & 63;
    const int wv   = t >> 6;                   // wave: rows 2wv, 2wv+1
    const int col  = lane & 15;                // B-col n == pixel in wave
    const int quad = lane >> 4;
    const int prow = r0 + 2 * wv + (col >> 3); // this lane's pixel row
    const int pcol = c0 + (col & 7);
    const int rem  = prow * WW + pcol;
    const int wy0  = r0 - 4;                   // window origin (16x16 px)
    const int wx0  = c0 - 4;
    const int cbh  = quad << 3;                // fallback channel base (g)

    __shared__ bf16_t V[256 * 72];             // 36 KB, pitch-skewed window

    const float* xb   = x + (size_t)b * CC * HW;
    const float* offp = offset + (size_t)b * (2 * KK) * HW + rem;
    const float* mp   = mask + (size_t)b * KK * HW + rem;

    // ---- stage 16x16-px window straight from NCHW fp32 (r18 verbatim) ----
    {
        const int i  = t >> 4;                 // window row 0..15
        const int j  = t & 15;                 // window col 0..15
        const int cy = min(max(wy0 + i, 0), HH - 1);
        const int cx = min(max(wx0 + j, 0), WW - 1);
        const float* src = xb + cy * WW + cx;
        bf16_t* dst = &V[t * 72];
#pragma unroll
        for (int s = 0; s < 8; ++s) {
            bf16x8 v;
#pragma unroll
            for (int e = 0; e < 8; ++e) v[e] = (bf16_t)src[(s * 8 + e) * HW];
            *(bf16x8*)(dst + (((s + t) & 7) << 3)) = v;  // skewed slot
        }
    }
    __syncthreads();

    f32x4 acc[4];
#pragma unroll
    for (int nt = 0; nt < 4; ++nt) acc[nt] = (f32x4){0.f, 0.f, 0.f, 0.f};
    const f32x4 zf = (f32x4){0.f, 0.f, 0.f, 0.f};

    float offy = offp[0];
    float offx = offp[HW];
    float mm   = mp[0];

#pragma unroll
    for (int k = 0; k < KK; ++k) {
        float n_offy = 0.f, n_offx = 0.f, n_mm = 0.f;
        if (k < KK - 1) {
            n_offy = offp[(2 * k + 2) * HW];
            n_offx = offp[(2 * k + 3) * HW];
            n_mm   = mp[(k + 1) * HW];
        }

        // ---- bilinear setup (exact reference semantics) ----
        float py = offy + (float)(k / KHW) + (float)(prow - 1);
        float px = offx + (float)(k % KHW) + (float)(pcol - 1);
        float fy0 = floorf(py), fx0 = floorf(px);
        float ly = py - fy0, lx = px - fx0;
        int y0 = (int)fy0, x0 = (int)fx0;
        int y1 = y0 + 1, x1 = x0 + 1;
        bool vy0 = (y0 >= 0) && (y0 < HH), vy1 = (y1 >= 0) && (y1 < HH);
        bool vx0 = (x0 >= 0) && (x0 < WW), vx1 = (x1 >= 0) && (x1 < WW);
        int cy0 = min(max(y0, 0), HH - 1), cy1 = min(max(y1, 0), HH - 1);
        int cx0 = min(max(x0, 0), WW - 1), cx1 = min(max(x1, 0), WW - 1);
        float w0 = (vy0 && vx0) ? mm * (1.0f - ly) * (1.0f - lx) : 0.0f;
        float w1 = (vy0 && vx1) ? mm * (1.0f - ly) * lx : 0.0f;
        float w2 = (vy1 && vx0) ? mm * ly * (1.0f - lx) : 0.0f;
        float w3 = (vy1 && vx1) ? mm * ly * lx : 0.0f;

        // ---- window-relative corner coords ----
        int uy0 = y0 - wy0, ux0 = x0 - wx0;
        int uy1 = uy0 + 1,  ux1 = ux0 + 1;
        bool iy0 = (unsigned)uy0 < 16u, iy1 = (unsigned)uy1 < 16u;
        bool ix0 = (unsigned)ux0 < 16u, ix1 = (unsigned)ux1 < 16u;
        int qy0 = min(max(uy0, 0), 15), qy1 = min(max(uy1, 0), 15);
        int qx0 = min(max(ux0, 0), 15), qx1 = min(max(ux1, 0), 15);
        int pa = qy0 * 16 + qx0, pb = qy0 * 16 + qx1;   // corner pixel ids
        int pc = qy1 * 16 + qx0, pd = qy1 * 16 + qx1;
        int sa = (quad + pa) & 7, sb = (quad + pb) & 7; // g-slots (h = ^4)
        int sc = (quad + pc) & 7, sd = (quad + pd) & 7;

        // ---- LDS gathers: g = ch quad*8.. (q=0 half), h = ch 32+quad*8 ----
        bf16x8 g00 = *(const bf16x8*)&V[pa * 72 + (sa << 3)];
        bf16x8 h00 = *(const bf16x8*)&V[pa * 72 + ((sa ^ 4) << 3)];
        bf16x8 g01 = *(const bf16x8*)&V[pb * 72 + (sb << 3)];
        bf16x8 h01 = *(const bf16x8*)&V[pb * 72 + ((sb ^ 4) << 3)];
        bf16x8 g10 = *(const bf16x8*)&V[pc * 72 + (sc << 3)];
        bf16x8 h10 = *(const bf16x8*)&V[pc * 72 + ((sc ^ 4) << 3)];
        bf16x8 g11 = *(const bf16x8*)&V[pd * 72 + (sd << 3)];
        bf16x8 h11 = *(const bf16x8*)&V[pd * 72 + ((sd ^ 4) << 3)];

        // ---- rare out-of-window fallback (exec-masked, NCHW fp32 source) --
        if (w0 != 0.0f && !(iy0 && ix0)) {
            const float* p = xb + (size_t)cbh * HW + cy0 * WW + cx0;
#pragma unroll
            for (int i = 0; i < 8; ++i) {
                g00[i] = (bf16_t)p[i * HW];
                h00[i] = (bf16_t)p[(32 + i) * HW];
            }
        }
        if (w1 != 0.0f && !(iy0 && ix1)) {
            const float* p = xb + (size_t)cbh * HW + cy0 * WW + cx1;
#pragma unroll
            for (int i = 0; i < 8; ++i) {
                g01[i] = (bf16_t)p[i * HW];
                h01[i] = (bf16_t)p[(32 + i) * HW];
            }
        }
        if (w2 != 0.0f && !(iy1 && ix0)) {
            const float* p = xb + (size_t)cbh * HW + cy1 * WW + cx0;
#pragma unroll
            for (int i = 0; i < 8; ++i) {
                g10[i] = (bf16_t)p[i * HW];
                h10[i] = (bf16_t)p[(32 + i) * HW];
            }
        }
        if (w3 != 0.0f && !(iy1 && ix1)) {
            const float* p = xb + (size_t)cbh * HW + cy1 * WW + cx1;
#pragma unroll
            for (int i = 0; i < 8; ++i) {
                g11[i] = (bf16_t)p[i * HW];
                h11[i] = (bf16_t)p[(32 + i) * HW];
            }
        }

        // ---- weight A-fragments for this tap (L2-hot, 8 x b128) ----
        bf16x8 wa0_0 = wf[(k * 8 + 0) * 64 + lane];      // q=0, nt=0..3
        bf16x8 wa0_1 = wf[(k * 8 + 1) * 64 + lane];
        bf16x8 wa0_2 = wf[(k * 8 + 2) * 64 + lane];
        bf16x8 wa0_3 = wf[(k * 8 + 3) * 64 + lane];
        bf16x8 wa1_0 = wf[(k * 8 + 4) * 64 + lane];      // q=1, nt=0..3
        bf16x8 wa1_1 = wf[(k * 8 + 5) * 64 + lane];
        bf16x8 wa1_2 = wf[(k * 8 + 6) * 64 + lane];
        bf16x8 wa1_3 = wf[(k * 8 + 7) * 64 + lane];

        // ---- corner-split MFMA: raw corner as B, weight as A; fold w_i ----
#define CORNER(gv, hv, wv_)                                                   \
        {                                                                     \
            f32x4 t0 = __builtin_amdgcn_mfma_f32_16x16x32_bf16(               \
                wa0_0, gv, zf, 0, 0, 0);                                      \
            f32x4 t1 = __builtin_amdgcn_mfma_f32_16x16x32_bf16(               \
                wa0_1, gv, zf, 0, 0, 0);                                      \
            f32x4 t2 = __builtin_amdgcn_mfma_f32_16x16x32_bf16(               \
                wa0_2, gv, zf, 0, 0, 0);                                      \
            f32x4 t3 = __builtin_amdgcn_mfma_f32_16x16x32_bf16(               \
                wa0_3, gv, zf, 0, 0, 0);                                      \
            t0 = __builtin_amdgcn_mfma_f32_16x16x32_bf16(wa1_0, hv, t0, 0, 0, 0); \
            t1 = __builtin_amdgcn_mfma_f32_16x16x32_bf16(wa1_1, hv, t1, 0, 0, 0); \
            t2 = __builtin_amdgcn_mfma_f32_16x16x32_bf16(wa1_2, hv, t2, 0, 0, 0); \
            t3 = __builtin_amdgcn_mfma_f32_16x16x32_bf16(wa1_3, hv, t3, 0, 0, 0); \
            _Pragma("unroll") for (int e = 0; e < 4; ++e) {                   \
                acc[0][e] += wv_ * t0[e];                                     \
                acc[1][e] += wv_ * t1[e];                                     \
                acc[2][e] += wv_ * t2[e];                                     \
                acc[3][e] += wv_ * t3[e];                                     \
            }                                                                 \
        }

        CORNER(g00, h00, w0)
        CORNER(g01, h01, w1)
        CORNER(g10, h10, w2)
        CORNER(g11, h11, w3)
#undef CORNER

        offy = n_offy;
        offx = n_offx;
        mm   = n_mm;
    }

    // ---- epilogue: D[row=o-sub=quad*4+e][col=pixel]; lane's pixel = rem ----
#pragma unroll
    for (int nt = 0; nt < 4; ++nt) {
        const int ob = nt * 16 + quad * 4;
        float* dst = out + (size_t)b * OO * HW + rem;
#pragma unroll
        for (int e = 0; e < 4; ++e) {
            dst[(size_t)(ob + e) * HW] = acc[nt][e] + bias[ob + e];
        }
    }
}

extern "C" void kernel_launch(void* const* d_in, const int* in_sizes, int n_in,
                              void* d_out, int out_size, void* d_ws,
                              size_t ws_size, hipStream_t stream) {
    const float* x      = (const float*)d_in[0];
    const float* offset = (const float*)d_in[1];
    const float* mask   = (const float*)d_in[2];
    const float* weight = (const float*)d_in[3];
    const float* bias   = (const float*)d_in[4];
    float* out = (float*)d_out;

    bf16_t* wfr = (bf16_t*)d_ws;                       // 72 KB

    int nw = OO * CC * KK;  // 36864
    wfrag_kernel<<<(nw + 255) / 256, 256, 0, stream>>>(weight, wfr);

    deform_conv_mfma<<<BB * (HW / 64), 256, 0, stream>>>(
        x, offset, mask, (const bf16x8*)wfr, bias, out);
}